// Round 13
// baseline (485.656 us; speedup 1.0000x reference)
//
#include <hip/hip_runtime.h>
#include <hip/hip_cooperative_groups.h>

namespace cg = cooperative_groups;

typedef _Float16 f16;
typedef _Float16 f16x8 __attribute__((ext_vector_type(8)));
typedef float f32x4 __attribute__((ext_vector_type(4)));

#define NROWS 131072
#define DIMS  64
#define KC    1024
#define BETA  0.25f
#define CHUNK 128          // rows per sum-chunk

// output offsets (floats)
#define OFF_Q      0
#define OFF_LOSS   8388608
#define OFF_EMB    8388609
#define OFF_COUNT  (8388609 + 65536)
#define OFF_EMBSUM (8388609 + 65536 + 1024)

// ws dword offsets — binned path, 1.856 MB total
#define WS_NORME  0            // float[1024]
#define WS_ET     1024         // float eT[K][64] exact
#define WS_EHT    66560        // f16[65536]
#define WS_ELT    99328        // f16[65536]
#define WS_IDX    132096       // int[131072]
#define WS_HIST   263168       // int[1024]
#define WS_OFF    264192       // int[1025] (pad 1040)
#define WS_CUR    265232       // int[1024]
#define WS_CCH    266256       // int[1025] cumulative chunks (pad 1040)
#define WS_RID    267296       // int[131072]
#define WS_SUMACC 398368       // float[1024][64]
#define WS_TOTAL_DW 463904

// fallback (R4) layout
#define WS_IDX_FB (1024 + 65536)

__global__ void vq_prep(const float* __restrict__ emb, float* __restrict__ ws,
                        f16* __restrict__ ehT, f16* __restrict__ elT,
                        int* __restrict__ hist, float* __restrict__ sumacc,
                        float* __restrict__ loss_out) {
    __shared__ float buf[64][65];
    const int t = threadIdx.x;
    const int k0 = blockIdx.x * 64;
    if (hist && blockIdx.x < 4) hist[blockIdx.x * 256 + t] = 0;
    if (sumacc) {
        #pragma unroll
        for (int j = 0; j < 16; ++j) sumacc[blockIdx.x * 4096 + j * 256 + t] = 0.f;
    }
    if (blockIdx.x == 0 && t == 0) *loss_out = 0.f;
    #pragma unroll
    for (int it = 0; it < 16; ++it) {
        int idx = it * 256 + t;
        int kk = idx & 63, d = idx >> 6;
        buf[kk][d] = emb[(size_t)d * KC + k0 + kk];   // coalesced over kk
    }
    __syncthreads();
    if (t < 64) {
        float s = 0.f;
        #pragma unroll 8
        for (int d = 0; d < 64; ++d) { float v = buf[t][d]; s += v * v; }
        ws[WS_NORME + k0 + t] = s;
    }
    #pragma unroll
    for (int it = 0; it < 16; ++it) {
        int idx = it * 256 + t;
        int d = idx & 63, kk = idx >> 6;
        float v = buf[kk][d];
        f16 hi = (f16)v;
        f16 lo = (f16)(v - (float)hi);
        ws[WS_ET + (size_t)(k0 + kk) * 64 + d] = v;   // coalesced over d
        ehT[(size_t)(k0 + kk) * 64 + d] = hi;
        elT[(size_t)(k0 + kk) * 64 + d] = lo;
    }
}

// [K5, proven 78us @ VGPR 60] 128 rows/block, 128-code chunks, plain
// 2-barrier loop, single acc chain. FROZEN — do not add epilogue code or acc
// chains: R6/R9/R11 all collapsed to scratch from exactly such additions.
template <bool DMA>
__launch_bounds__(256, 4)
__global__ void vq_main_t(const float* __restrict__ x, const f16* __restrict__ ehT,
                          const f16* __restrict__ elT, const float* __restrict__ ws,
                          float* __restrict__ q_out, int* __restrict__ idxout,
                          int* __restrict__ hist) {
    __shared__ f16 eh[128 * 64];     // XOR-swizzled [code][d]
    __shared__ f16 el[128 * 64];
    __shared__ float nEl[1024];
    __shared__ int best_k[128];

    const int t    = threadIdx.x;
    const int lane = t & 63;
    const int wv   = t >> 6;         // 4 waves, 32 rows each
    const int brow = blockIdx.x * 128;
    const int l15  = lane & 15;
    const int l4   = lane >> 4;

    // preload normE (consumed via MFMA C-operand init)
    #pragma unroll
    for (int j = 0; j < 4; ++j) nEl[t + j * 256] = ws[WS_NORME + t + j * 256];

    // A fragments: rows of x as f16 hi/lo. A layout: row=lane&15, k=(lane>>4)*8+j
    f16x8 ahi[2][2], alo[2][2];
    #pragma unroll
    for (int rt = 0; rt < 2; ++rt) {
        int row = brow + wv * 32 + rt * 16 + l15;
        #pragma unroll
        for (int ks = 0; ks < 2; ++ks) {
            int d0 = ks * 32 + l4 * 8;
            const float* p = x + (size_t)row * 64 + d0;
            float4 v0 = *(const float4*)p;
            float4 v1 = *(const float4*)(p + 4);
            float vv[8] = {v0.x, v0.y, v0.z, v0.w, v1.x, v1.y, v1.z, v1.w};
            f16x8 h, l;
            #pragma unroll
            for (int j = 0; j < 8; ++j) {
                f16 hj = (f16)vv[j];
                h[j] = hj;
                l[j] = (f16)(vv[j] - (float)hj);
            }
            ahi[rt][ks] = h; alo[rt][ks] = l;
        }
    }

    // per-thread pre-swizzled staging source offsets (both-sides rule #21:
    // inverse-swizzled global source + linear LDS dest; read applies same XOR)
    int swz[4];
    #pragma unroll
    for (int it = 0; it < 4; ++it) {
        int n = (it * 256 + t) * 16;
        int code = n >> 7, inner = n & 127;
        swz[it] = (code << 7) | (inner ^ ((code & 7) << 4));
    }

    float bmax[2][4];
    int   bidx[2][4];
    #pragma unroll
    for (int rt = 0; rt < 2; ++rt)
        #pragma unroll
        for (int r = 0; r < 4; ++r) { bmax[rt][r] = -1e30f; bidx[rt][r] = 0; }

    for (int kc0 = 0; kc0 < KC; kc0 += 128) {
        __syncthreads();
        if constexpr (DMA) {
            #pragma unroll
            for (int it = 0; it < 4; ++it) {
                int lo = (it * 256 + wv * 64) * 16;   // wave-uniform base, lane*16 auto
                const char* gh = (const char*)ehT + (size_t)kc0 * 128 + swz[it];
                const char* gl = (const char*)elT + (size_t)kc0 * 128 + swz[it];
                __builtin_amdgcn_global_load_lds(
                    (const __attribute__((address_space(1))) void*)gh,
                    (__attribute__((address_space(3))) void*)((char*)eh + lo), 16, 0, 0);
                __builtin_amdgcn_global_load_lds(
                    (const __attribute__((address_space(1))) void*)gl,
                    (__attribute__((address_space(3))) void*)((char*)el + lo), 16, 0, 0);
            }
        } else {
            #pragma unroll
            for (int it = 0; it < 4; ++it) {
                int n = (it * 256 + t) * 16;
                float4 vh = *(const float4*)((const char*)ehT + (size_t)kc0 * 128 + n);
                float4 vl = *(const float4*)((const char*)elT + (size_t)kc0 * 128 + n);
                *(float4*)((char*)eh + swz[it]) = vh;
                *(float4*)((char*)el + swz[it]) = vl;
            }
        }
        __syncthreads();

        #pragma unroll
        for (int ct = 0; ct < 8; ++ct) {
            int code = ct * 16 + l15;             // B col = lane&15
            f16x8 bh[2], bl[2];
            #pragma unroll
            for (int ks = 0; ks < 2; ++ks) {
                int inner = ks * 64 + l4 * 16;    // k = (lane>>4)*8 + j
                int off = (code << 7) | (inner ^ ((code & 7) << 4));
                bh[ks] = *(const f16x8*)((char*)eh + off);
                bl[ks] = *(const f16x8*)((char*)el + off);
            }
            int gcol = kc0 + code;
            float c0 = -0.5f * nEl[gcol];         // dist = -2*(sim - nE/2): track max
            #pragma unroll
            for (int rt = 0; rt < 2; ++rt) {
                f32x4 acc = {c0, c0, c0, c0};
                acc = __builtin_amdgcn_mfma_f32_16x16x32_f16(ahi[rt][0], bh[0], acc, 0, 0, 0);
                acc = __builtin_amdgcn_mfma_f32_16x16x32_f16(ahi[rt][1], bh[1], acc, 0, 0, 0);
                acc = __builtin_amdgcn_mfma_f32_16x16x32_f16(alo[rt][0], bh[0], acc, 0, 0, 0);
                acc = __builtin_amdgcn_mfma_f32_16x16x32_f16(alo[rt][1], bh[1], acc, 0, 0, 0);
                acc = __builtin_amdgcn_mfma_f32_16x16x32_f16(ahi[rt][0], bl[0], acc, 0, 0, 0);
                acc = __builtin_amdgcn_mfma_f32_16x16x32_f16(ahi[rt][1], bl[1], acc, 0, 0, 0);
                // C/D layout: col = lane&15, row = (lane>>4)*4 + reg
                #pragma unroll
                for (int r = 0; r < 4; ++r) {
                    if (acc[r] > bmax[rt][r]) { bmax[rt][r] = acc[r]; bidx[rt][r] = gcol; }
                }
            }
        }
    }

    // argmax reduce across the 16 lanes holding the same row (tie -> lower k)
    #pragma unroll
    for (int rt = 0; rt < 2; ++rt) {
        #pragma unroll
        for (int r = 0; r < 4; ++r) {
            float a = bmax[rt][r]; int k = bidx[rt][r];
            #pragma unroll
            for (int m = 1; m <= 8; m <<= 1) {
                float a2 = __shfl_xor(a, m, 64);
                int   k2 = __shfl_xor(k, m, 64);
                if (a2 > a || (a2 == a && k2 < k)) { a = a2; k = k2; }
            }
            if (l15 == 0) {
                int rloc = wv * 32 + rt * 16 + l4 * 4 + r;
                best_k[rloc] = k;
                if (hist) atomicAdd(&hist[k], 1);
            }
        }
    }
    __syncthreads();

    // epilogue: idx write + coalesced q gather from exact fp32 eT.
    if (t < 128) idxout[brow + t] = best_k[t];
    const float* eT = ws + WS_ET;
    #pragma unroll 4
    for (int it = 0; it < 32; ++it) {
        int r = it * 4 + wv;
        int k = best_k[r];                        // wave-uniform broadcast
        q_out[(size_t)(brow + r) * 64 + lane] = eT[(size_t)k * 64 + lane];
    }
}

// Cooperative tail: scan -> bin -> chunked sums -> finalize, with grid.sync
// between phases (replaces 4 launches + their drain gaps).
__launch_bounds__(256, 4)
__global__ void vq_cluster(const float* __restrict__ x, float* __restrict__ ws,
                           const float* __restrict__ scount,
                           const float* __restrict__ esum,
                           float* __restrict__ out) {
    __shared__ int wp1[4], wp2[4];
    __shared__ float ssum[4][64];
    __shared__ float sl[4];

    cg::grid_group grid = cg::this_grid();
    int* wsI = (int*)ws;
    const int t    = threadIdx.x;
    const int lane = t & 63;
    const int wv   = t >> 6;

    // ---- Phase A: dual prefix scan of hist (block 0; logic proven in R11) ----
    if (blockIdx.x == 0) {
        int h[4], m[4];
        const int base = t * 4;
        #pragma unroll
        for (int j = 0; j < 4; ++j) h[j] = wsI[WS_HIST + base + j];
        int hs = 0, ms = 0;
        #pragma unroll
        for (int j = 0; j < 4; ++j) { m[j] = (h[j] + CHUNK - 1) >> 7; hs += h[j]; ms += m[j]; }
        int v1 = hs, v2 = ms;
        #pragma unroll
        for (int o = 1; o < 64; o <<= 1) {
            int a = __shfl_up(v1, o, 64), b = __shfl_up(v2, o, 64);
            if (lane >= o) { v1 += a; v2 += b; }
        }
        if (lane == 63) { wp1[wv] = v1; wp2[wv] = v2; }
        __syncthreads();
        int add1 = 0, add2 = 0;
        #pragma unroll
        for (int w = 0; w < 4; ++w) if (w < wv) { add1 += wp1[w]; add2 += wp2[w]; }
        int e1 = v1 - hs + add1;
        int e2 = v2 - ms + add2;
        #pragma unroll
        for (int j = 0; j < 4; ++j) {
            wsI[WS_OFF + base + j] = e1;
            wsI[WS_CUR + base + j] = e1;
            wsI[WS_CCH + base + j] = e2;
            out[OFF_COUNT + base + j] = scount[base + j] + (float)h[j];
            e1 += h[j]; e2 += m[j];
        }
        if (t == 255) { wsI[WS_OFF + 1024] = e1; wsI[WS_CCH + 1024] = e2; }
    }
    grid.sync();

    // ---- Phase B: bin rows (cursor atomics; same-line fast pattern) ----
    if (t < 128) {
        int i = blockIdx.x * 128 + t;
        int k = wsI[WS_IDX + i];
        int pos = atomicAdd(&wsI[WS_CUR + k], 1);
        wsI[WS_RID + pos] = i;
    }
    grid.sync();

    // ---- Phase C: grid-stride chunked sums (4-wave variant of proven body) ----
    const int NC = wsI[WS_CCH + 1024];
    const int* rid = wsI + WS_RID;
    for (int c = blockIdx.x; c < NC; c += (int)gridDim.x) {
        int lo = 0, hi = 1024;
        while (hi - lo > 1) {
            int mid = (lo + hi) >> 1;
            if (wsI[WS_CCH + mid] <= c) lo = mid; else hi = mid;
        }
        const int k    = lo;
        const int base = wsI[WS_OFF + k] + (c - wsI[WS_CCH + k]) * CHUNK;
        const int endr = min(base + CHUNK, wsI[WS_OFF + k + 1]);
        const float ek = ws[WS_ET + (size_t)k * 64 + lane];

        float sA = 0.f, sB = 0.f, lA = 0.f, lB = 0.f;
        int i = base + wv;
        for (; i + 4 < endr; i += 8) {
            int rA = rid[i], rB = rid[i + 4];
            float xA = x[(size_t)rA * 64 + lane];
            float xB = x[(size_t)rB * 64 + lane];
            sA += xA; float dA = xA - ek; lA += dA * dA;
            sB += xB; float dB = xB - ek; lB += dB * dB;
        }
        if (i < endr) {
            int rA = rid[i];
            float xA = x[(size_t)rA * 64 + lane];
            sA += xA; float dA = xA - ek; lA += dA * dA;
        }
        float sum = sA + sB, ls = lA + lB;
        #pragma unroll
        for (int o = 32; o > 0; o >>= 1) ls += __shfl_down(ls, o);
        ssum[wv][lane] = sum;
        if (lane == 0) sl[wv] = ls;
        __syncthreads();
        if (wv == 0) {
            float s = ssum[0][lane] + ssum[1][lane] + ssum[2][lane] + ssum[3][lane];
            atomicAdd(&ws[WS_SUMACC + (size_t)k * 64 + lane], s);
            if (lane == 0)
                atomicAdd(&out[OFF_LOSS],
                          (sl[0] + sl[1] + sl[2] + sl[3]) * (BETA / ((float)NROWS * (float)DIMS)));
        }
        __syncthreads();             // ssum/sl reuse next grid-stride iter
    }
    grid.sync();

    // ---- Phase D: finalize emb/embsum (blocks 0..255, coalesced) ----
    if (blockIdx.x < 256) {
        int i = blockIdx.x * 256 + t;     // i = d*1024 + k
        int d = i >> 10, k = i & 1023;
        float ns = esum[i] + ws[WS_SUMACC + (size_t)k * 64 + d];
        float cf = out[OFF_COUNT + k];
        out[OFF_EMBSUM + i] = ns;
        out[OFF_EMB    + i] = ns / fmaxf(cf, 1e-5f);
    }
}

// fallback: scan-based cluster update, one block per code (proven R4 path).
__launch_bounds__(256)
__global__ void vq_scatter(const float* __restrict__ x, const float* __restrict__ ws,
                           const int* __restrict__ idx, const float* __restrict__ scount,
                           const float* __restrict__ esum, float* __restrict__ out) {
    __shared__ float ssum[4][64];
    __shared__ float slsum[4];
    __shared__ int   scnt[4];
    const int k    = blockIdx.x;
    const int t    = threadIdx.x;
    const int lane = t & 63;
    const int wv   = t >> 6;
    const float ek = ws[WS_ET + (size_t)k * 64 + lane];
    const int4* idx4 = (const int4*)idx;
    float sum = 0.f, lsum = 0.f;
    int cnt = 0;
    const int base = wv * (NROWS / 16);
    for (int i0 = 0; i0 < NROWS / 16; i0 += 64) {
        int4 v = idx4[base + i0 + lane];
        #pragma unroll
        for (int j = 0; j < 4; ++j) {
            int vj = (j == 0) ? v.x : (j == 1) ? v.y : (j == 2) ? v.z : v.w;
            unsigned long long m = __ballot(vj == k);
            cnt += (int)__popcll(m);
            while (m) {
                int b = __builtin_ctzll(m);
                m &= m - 1;
                int row = (base + i0 + b) * 4 + j;
                float xv = x[(size_t)row * 64 + lane];
                sum += xv;
                float diff = xv - ek;
                lsum += diff * diff;
            }
        }
    }
    #pragma unroll
    for (int o = 32; o > 0; o >>= 1) lsum += __shfl_down(lsum, o);
    ssum[wv][lane] = sum;
    if (lane == 0) { scnt[wv] = cnt; slsum[wv] = lsum; }
    __syncthreads();
    if (wv == 0) {
        float s = ssum[0][lane] + ssum[1][lane] + ssum[2][lane] + ssum[3][lane];
        int   c = scnt[0] + scnt[1] + scnt[2] + scnt[3];
        float cf = scount[k] + (float)c;
        float ns = esum[(size_t)lane * KC + k] + s;
        out[OFF_EMBSUM + (size_t)lane * KC + k] = ns;
        out[OFF_EMB    + (size_t)lane * KC + k] = ns / fmaxf(cf, 1e-5f);
        if (lane == 0) {
            out[OFF_COUNT + k] = cf;
            float lp = slsum[0] + slsum[1] + slsum[2] + slsum[3];
            atomicAdd(&out[OFF_LOSS], lp * (BETA / ((float)NROWS * (float)DIMS)));
        }
    }
}

extern "C" void kernel_launch(void* const* d_in, const int* in_sizes, int n_in,
                              void* d_out, int out_size, void* d_ws, size_t ws_size,
                              hipStream_t stream) {
    const float* x      = (const float*)d_in[0];
    const float* emb    = (const float*)d_in[1];
    const float* scount = (const float*)d_in[2];
    const float* esum   = (const float*)d_in[3];
    float* out = (float*)d_out;
    float* ws  = (float*)d_ws;

    const bool binned = ws_size >= (size_t)WS_TOTAL_DW * 4;
    if (binned) {
        f16* ehT = (f16*)(ws + WS_EHT);
        f16* elT = (f16*)(ws + WS_ELT);
        int* wsI = (int*)ws;
        vq_prep<<<KC / 64, 256, 0, stream>>>(emb, ws, ehT, elT, wsI + WS_HIST,
                                             ws + WS_SUMACC, out + OFF_LOSS);
        vq_main_t<true><<<NROWS / 128, 256, 0, stream>>>(x, ehT, elT, ws, out,
                                                         wsI + WS_IDX, wsI + WS_HIST);
        {
            const float* xa = x; float* wsa = ws;
            const float* sca = scount; const float* esa = esum; float* outa = out;
            void* args[] = {(void*)&xa, (void*)&wsa, (void*)&sca, (void*)&esa,
                            (void*)&outa};
            hipLaunchCooperativeKernel((const void*)vq_cluster, dim3(1024),
                                       dim3(256), args, 0, stream);
        }
    } else {
        f16* ehT = (f16*)(out + OFF_EMBSUM);   // stashed in output, overwritten later
        f16* elT = ehT + KC * DIMS;
        int* idx = (int*)ws + WS_IDX_FB;
        vq_prep<<<KC / 64, 256, 0, stream>>>(emb, ws, ehT, elT, nullptr, nullptr,
                                             out + OFF_LOSS);
        vq_main_t<false><<<NROWS / 128, 256, 0, stream>>>(x, ehT, elT, ws, out,
                                                          idx, nullptr);
        vq_scatter<<<KC, 256, 0, stream>>>(x, ws, idx, scount, esum, out);
    }
}

// Round 14
// 220.064 us; speedup vs baseline: 2.2069x; 2.2069x over previous
//
#include <hip/hip_runtime.h>

typedef _Float16 f16;
typedef _Float16 f16x8 __attribute__((ext_vector_type(8)));
typedef float f32x4 __attribute__((ext_vector_type(4)));

#define NROWS 131072
#define DIMS  64
#define KC    1024
#define BETA  0.25f
#define CHUNK 128          // rows per sum-chunk block

// output offsets (floats)
#define OFF_Q      0
#define OFF_LOSS   8388608
#define OFF_EMB    8388609
#define OFF_COUNT  (8388609 + 65536)
#define OFF_EMBSUM (8388609 + 65536 + 1024)

// ws dword offsets — binned path, 1.86 MB total
#define WS_NORME  0            // float[1024]
#define WS_ET     1024         // float eT[K][64] exact
#define WS_EHT    66560        // f16[65536]
#define WS_ELT    99328        // f16[65536]
#define WS_IDX    132096       // int[131072]
#define WS_HIST   263168       // int[1024]
#define WS_OFF    264192       // int[1025] (pad 1040)
#define WS_CUR    265232       // int[1024]
#define WS_CCH    266256       // int[1025] cumulative chunks (pad 1040)
#define WS_RID    267296       // int[131072]
#define WS_SUMACC 398368       // float[1024][64]
#define WS_DONE   463904       // int[1024] per-code completion tickets
#define WS_TOTAL_DW 464928

// fallback (R4) layout
#define WS_IDX_FB (1024 + 65536)

__global__ void vq_prep(const float* __restrict__ emb, float* __restrict__ ws,
                        f16* __restrict__ ehT, f16* __restrict__ elT,
                        int* __restrict__ hist, float* __restrict__ sumacc,
                        float* __restrict__ loss_out) {
    __shared__ float buf[64][65];
    const int t = threadIdx.x;
    const int k0 = blockIdx.x * 64;
    if (hist && blockIdx.x < 4) {
        hist[blockIdx.x * 256 + t] = 0;
        ((int*)ws)[WS_DONE + blockIdx.x * 256 + t] = 0;
    }
    if (sumacc) {
        #pragma unroll
        for (int j = 0; j < 16; ++j) sumacc[blockIdx.x * 4096 + j * 256 + t] = 0.f;
    }
    if (blockIdx.x == 0 && t == 0) *loss_out = 0.f;
    #pragma unroll
    for (int it = 0; it < 16; ++it) {
        int idx = it * 256 + t;
        int kk = idx & 63, d = idx >> 6;
        buf[kk][d] = emb[(size_t)d * KC + k0 + kk];   // coalesced over kk
    }
    __syncthreads();
    if (t < 64) {
        float s = 0.f;
        #pragma unroll 8
        for (int d = 0; d < 64; ++d) { float v = buf[t][d]; s += v * v; }
        ws[WS_NORME + k0 + t] = s;
    }
    #pragma unroll
    for (int it = 0; it < 16; ++it) {
        int idx = it * 256 + t;
        int d = idx & 63, kk = idx >> 6;
        float v = buf[kk][d];
        f16 hi = (f16)v;
        f16 lo = (f16)(v - (float)hi);
        ws[WS_ET + (size_t)(k0 + kk) * 64 + d] = v;   // coalesced over d
        ehT[(size_t)(k0 + kk) * 64 + d] = hi;
        elT[(size_t)(k0 + kk) * 64 + d] = lo;
    }
}

// [K5, proven 78us @ VGPR 60] 128 rows/block, 128-code chunks, plain
// 2-barrier loop, single acc chain. FROZEN — do not add epilogue code or acc
// chains: R6/R9/R11 all collapsed to scratch from exactly such additions.
template <bool DMA>
__launch_bounds__(256, 4)
__global__ void vq_main_t(const float* __restrict__ x, const f16* __restrict__ ehT,
                          const f16* __restrict__ elT, const float* __restrict__ ws,
                          float* __restrict__ q_out, int* __restrict__ idxout,
                          int* __restrict__ hist) {
    __shared__ f16 eh[128 * 64];     // XOR-swizzled [code][d]
    __shared__ f16 el[128 * 64];
    __shared__ float nEl[1024];
    __shared__ int best_k[128];

    const int t    = threadIdx.x;
    const int lane = t & 63;
    const int wv   = t >> 6;         // 4 waves, 32 rows each
    const int brow = blockIdx.x * 128;
    const int l15  = lane & 15;
    const int l4   = lane >> 4;

    // preload normE (consumed via MFMA C-operand init)
    #pragma unroll
    for (int j = 0; j < 4; ++j) nEl[t + j * 256] = ws[WS_NORME + t + j * 256];

    // A fragments: rows of x as f16 hi/lo. A layout: row=lane&15, k=(lane>>4)*8+j
    f16x8 ahi[2][2], alo[2][2];
    #pragma unroll
    for (int rt = 0; rt < 2; ++rt) {
        int row = brow + wv * 32 + rt * 16 + l15;
        #pragma unroll
        for (int ks = 0; ks < 2; ++ks) {
            int d0 = ks * 32 + l4 * 8;
            const float* p = x + (size_t)row * 64 + d0;
            float4 v0 = *(const float4*)p;
            float4 v1 = *(const float4*)(p + 4);
            float vv[8] = {v0.x, v0.y, v0.z, v0.w, v1.x, v1.y, v1.z, v1.w};
            f16x8 h, l;
            #pragma unroll
            for (int j = 0; j < 8; ++j) {
                f16 hj = (f16)vv[j];
                h[j] = hj;
                l[j] = (f16)(vv[j] - (float)hj);
            }
            ahi[rt][ks] = h; alo[rt][ks] = l;
        }
    }

    // per-thread pre-swizzled staging source offsets (both-sides rule #21:
    // inverse-swizzled global source + linear LDS dest; read applies same XOR)
    int swz[4];
    #pragma unroll
    for (int it = 0; it < 4; ++it) {
        int n = (it * 256 + t) * 16;
        int code = n >> 7, inner = n & 127;
        swz[it] = (code << 7) | (inner ^ ((code & 7) << 4));
    }

    float bmax[2][4];
    int   bidx[2][4];
    #pragma unroll
    for (int rt = 0; rt < 2; ++rt)
        #pragma unroll
        for (int r = 0; r < 4; ++r) { bmax[rt][r] = -1e30f; bidx[rt][r] = 0; }

    for (int kc0 = 0; kc0 < KC; kc0 += 128) {
        __syncthreads();
        if constexpr (DMA) {
            #pragma unroll
            for (int it = 0; it < 4; ++it) {
                int lo = (it * 256 + wv * 64) * 16;   // wave-uniform base, lane*16 auto
                const char* gh = (const char*)ehT + (size_t)kc0 * 128 + swz[it];
                const char* gl = (const char*)elT + (size_t)kc0 * 128 + swz[it];
                __builtin_amdgcn_global_load_lds(
                    (const __attribute__((address_space(1))) void*)gh,
                    (__attribute__((address_space(3))) void*)((char*)eh + lo), 16, 0, 0);
                __builtin_amdgcn_global_load_lds(
                    (const __attribute__((address_space(1))) void*)gl,
                    (__attribute__((address_space(3))) void*)((char*)el + lo), 16, 0, 0);
            }
        } else {
            #pragma unroll
            for (int it = 0; it < 4; ++it) {
                int n = (it * 256 + t) * 16;
                float4 vh = *(const float4*)((const char*)ehT + (size_t)kc0 * 128 + n);
                float4 vl = *(const float4*)((const char*)elT + (size_t)kc0 * 128 + n);
                *(float4*)((char*)eh + swz[it]) = vh;
                *(float4*)((char*)el + swz[it]) = vl;
            }
        }
        __syncthreads();

        #pragma unroll
        for (int ct = 0; ct < 8; ++ct) {
            int code = ct * 16 + l15;             // B col = lane&15
            f16x8 bh[2], bl[2];
            #pragma unroll
            for (int ks = 0; ks < 2; ++ks) {
                int inner = ks * 64 + l4 * 16;    // k = (lane>>4)*8 + j
                int off = (code << 7) | (inner ^ ((code & 7) << 4));
                bh[ks] = *(const f16x8*)((char*)eh + off);
                bl[ks] = *(const f16x8*)((char*)el + off);
            }
            int gcol = kc0 + code;
            float c0 = -0.5f * nEl[gcol];         // dist = -2*(sim - nE/2): track max
            #pragma unroll
            for (int rt = 0; rt < 2; ++rt) {
                f32x4 acc = {c0, c0, c0, c0};
                acc = __builtin_amdgcn_mfma_f32_16x16x32_f16(ahi[rt][0], bh[0], acc, 0, 0, 0);
                acc = __builtin_amdgcn_mfma_f32_16x16x32_f16(ahi[rt][1], bh[1], acc, 0, 0, 0);
                acc = __builtin_amdgcn_mfma_f32_16x16x32_f16(alo[rt][0], bh[0], acc, 0, 0, 0);
                acc = __builtin_amdgcn_mfma_f32_16x16x32_f16(alo[rt][1], bh[1], acc, 0, 0, 0);
                acc = __builtin_amdgcn_mfma_f32_16x16x32_f16(ahi[rt][0], bl[0], acc, 0, 0, 0);
                acc = __builtin_amdgcn_mfma_f32_16x16x32_f16(ahi[rt][1], bl[1], acc, 0, 0, 0);
                // C/D layout: col = lane&15, row = (lane>>4)*4 + reg
                #pragma unroll
                for (int r = 0; r < 4; ++r) {
                    if (acc[r] > bmax[rt][r]) { bmax[rt][r] = acc[r]; bidx[rt][r] = gcol; }
                }
            }
        }
    }

    // argmax reduce across the 16 lanes holding the same row (tie -> lower k)
    #pragma unroll
    for (int rt = 0; rt < 2; ++rt) {
        #pragma unroll
        for (int r = 0; r < 4; ++r) {
            float a = bmax[rt][r]; int k = bidx[rt][r];
            #pragma unroll
            for (int m = 1; m <= 8; m <<= 1) {
                float a2 = __shfl_xor(a, m, 64);
                int   k2 = __shfl_xor(k, m, 64);
                if (a2 > a || (a2 == a && k2 < k)) { a = a2; k = k2; }
            }
            if (l15 == 0) {
                int rloc = wv * 32 + rt * 16 + l4 * 4 + r;
                best_k[rloc] = k;
                if (hist) atomicAdd(&hist[k], 1);
            }
        }
    }
    __syncthreads();

    // epilogue: idx write + coalesced q gather from exact fp32 eT.
    if (t < 128) idxout[brow + t] = best_k[t];
    const float* eT = ws + WS_ET;
    #pragma unroll 4
    for (int it = 0; it < 32; ++it) {
        int r = it * 4 + wv;
        int k = best_k[r];                        // wave-uniform broadcast
        q_out[(size_t)(brow + r) * 64 + lane] = eT[(size_t)k * 64 + lane];
    }
}

// 1 block, 1024 threads: shfl prefix scans of hist (-> offsets/cursors) and
// max(1, ceil(hist/CHUNK)) (-> chunk table; empty codes get one chunk so the
// fused finalize covers them); writes count output.
__global__ void vq_scan(const float* __restrict__ scount, int* __restrict__ wsI,
                        float* __restrict__ out) {
    __shared__ int wincl[16];
    __shared__ int wincl2[16];
    const int t = threadIdx.x;
    const int lane = t & 63, wv = t >> 6;
    int h = wsI[WS_HIST + t];
    int m = (h + CHUNK - 1) >> 7;    // chunks for this code
    if (m == 0) m = 1;               // empty codes still finalize
    int v = h, u = m;
    #pragma unroll
    for (int o = 1; o < 64; o <<= 1) {
        int a = __shfl_up(v, o, 64);
        int b = __shfl_up(u, o, 64);
        if (lane >= o) { v += a; u += b; }
    }
    if (lane == 63) { wincl[wv] = v; wincl2[wv] = u; }
    __syncthreads();
    if (t < 16) {
        int s = wincl[t], s2 = wincl2[t];
        #pragma unroll
        for (int o = 1; o < 16; o <<= 1) {
            int a = __shfl_up(s, o, 64);
            int b = __shfl_up(s2, o, 64);
            if (t >= o) { s += a; s2 += b; }
        }
        wincl[t] = s; wincl2[t] = s2;
    }
    __syncthreads();
    int incl  = v + (wv ? wincl[wv - 1] : 0);
    int incl2 = u + (wv ? wincl2[wv - 1] : 0);
    wsI[WS_OFF + t] = incl - h;
    wsI[WS_CUR + t] = incl - h;
    wsI[WS_CCH + t] = incl2 - m;
    if (t == 1023) { wsI[WS_OFF + 1024] = incl; wsI[WS_CCH + 1024] = incl2; }
    out[OFF_COUNT + t] = scount[t] + (float)h;
}

// bin rows by code: 131072 same-line cursor atomics + rowid writes.
__global__ void vq_bin(int* __restrict__ wsI) {
    const int i = blockIdx.x * blockDim.x + threadIdx.x;
    int k = wsI[WS_IDX + i];
    int pos = atomicAdd(&wsI[WS_CUR + k], 1);
    wsI[WS_RID + pos] = i;
}

// one block per CHUNK of a bin (skew-proof): partial sums -> SUMACC atomics;
// the LAST chunk of each code (done-ticket) finalizes that code's outputs.
__launch_bounds__(512)
__global__ void vq_sumchunk(const float* __restrict__ x, float* __restrict__ ws,
                            const float* __restrict__ esum, float* __restrict__ out) {
    __shared__ float ssum[8][64];
    __shared__ float sl[8];
    const int t    = threadIdx.x;
    const int lane = t & 63;
    const int wv   = t >> 6;
    int* wsI = (int*)ws;
    const int c = blockIdx.x;
    if (c >= wsI[WS_CCH + 1024]) return;
    // binary search: largest k with cch[k] <= c
    int lo = 0, hi = 1024;
    while (hi - lo > 1) {
        int mid = (lo + hi) >> 1;
        if (wsI[WS_CCH + mid] <= c) lo = mid; else hi = mid;
    }
    const int k    = lo;
    const int nchk = wsI[WS_CCH + k + 1] - wsI[WS_CCH + k];
    const int base = wsI[WS_OFF + k] + (c - wsI[WS_CCH + k]) * CHUNK;
    const int endr = min(base + CHUNK, wsI[WS_OFF + k + 1]);
    const int* rid = wsI + WS_RID;
    const float ek = ws[WS_ET + (size_t)k * 64 + lane];

    float sA = 0.f, sB = 0.f, lA = 0.f, lB = 0.f;
    int i = base + wv;
    for (; i + 8 < endr; i += 16) {
        int rA = rid[i], rB = rid[i + 8];
        float xA = x[(size_t)rA * 64 + lane];
        float xB = x[(size_t)rB * 64 + lane];
        sA += xA; float dA = xA - ek; lA += dA * dA;
        sB += xB; float dB = xB - ek; lB += dB * dB;
    }
    if (i < endr) {
        int rA = rid[i];
        float xA = x[(size_t)rA * 64 + lane];
        sA += xA; float dA = xA - ek; lA += dA * dA;
    }
    float sum = sA + sB, ls = lA + lB;
    #pragma unroll
    for (int o = 32; o > 0; o >>= 1) ls += __shfl_down(ls, o);
    ssum[wv][lane] = sum;
    if (lane == 0) sl[wv] = ls;
    __syncthreads();
    if (wv == 0) {
        float s = 0.f;
        #pragma unroll
        for (int w = 0; w < 8; ++w) s += ssum[w][lane];
        atomicAdd(&ws[WS_SUMACC + (size_t)k * 64 + lane], s);   // coalesced line
        if (lane == 0) {
            float lp = 0.f;
            #pragma unroll
            for (int w = 0; w < 8; ++w) lp += sl[w];
            atomicAdd(&out[OFF_LOSS], lp * (BETA / ((float)NROWS * (float)DIMS)));
        }
        // done-ticket: last chunk of code k finalizes its outputs
        int lastFlag = 0;
        if (lane == 0) {
            __threadfence();
            int prev = __hip_atomic_fetch_add(wsI + WS_DONE + k, 1, __ATOMIC_ACQ_REL,
                                              __HIP_MEMORY_SCOPE_AGENT);
            lastFlag = (prev == nchk - 1);
        }
        lastFlag = __shfl(lastFlag, 0, 64);
        if (lastFlag) {
            float sa = __hip_atomic_load(&ws[WS_SUMACC + (size_t)k * 64 + lane],
                                         __ATOMIC_RELAXED, __HIP_MEMORY_SCOPE_AGENT);
            float ns = esum[(size_t)lane * KC + k] + sa;
            float cf = out[OFF_COUNT + k];
            out[OFF_EMBSUM + (size_t)lane * KC + k] = ns;
            out[OFF_EMB    + (size_t)lane * KC + k] = ns / fmaxf(cf, 1e-5f);
        }
    }
}

// fallback: scan-based cluster update, one block per code (proven R4 path).
__launch_bounds__(256)
__global__ void vq_scatter(const float* __restrict__ x, const float* __restrict__ ws,
                           const int* __restrict__ idx, const float* __restrict__ scount,
                           const float* __restrict__ esum, float* __restrict__ out) {
    __shared__ float ssum[4][64];
    __shared__ float slsum[4];
    __shared__ int   scnt[4];
    const int k    = blockIdx.x;
    const int t    = threadIdx.x;
    const int lane = t & 63;
    const int wv   = t >> 6;
    const float ek = ws[WS_ET + (size_t)k * 64 + lane];
    const int4* idx4 = (const int4*)idx;
    float sum = 0.f, lsum = 0.f;
    int cnt = 0;
    const int base = wv * (NROWS / 16);
    for (int i0 = 0; i0 < NROWS / 16; i0 += 64) {
        int4 v = idx4[base + i0 + lane];
        #pragma unroll
        for (int j = 0; j < 4; ++j) {
            int vj = (j == 0) ? v.x : (j == 1) ? v.y : (j == 2) ? v.z : v.w;
            unsigned long long m = __ballot(vj == k);
            cnt += (int)__popcll(m);
            while (m) {
                int b = __builtin_ctzll(m);
                m &= m - 1;
                int row = (base + i0 + b) * 4 + j;
                float xv = x[(size_t)row * 64 + lane];
                sum += xv;
                float diff = xv - ek;
                lsum += diff * diff;
            }
        }
    }
    #pragma unroll
    for (int o = 32; o > 0; o >>= 1) lsum += __shfl_down(lsum, o);
    ssum[wv][lane] = sum;
    if (lane == 0) { scnt[wv] = cnt; slsum[wv] = lsum; }
    __syncthreads();
    if (wv == 0) {
        float s = ssum[0][lane] + ssum[1][lane] + ssum[2][lane] + ssum[3][lane];
        int   c = scnt[0] + scnt[1] + scnt[2] + scnt[3];
        float cf = scount[k] + (float)c;
        float ns = esum[(size_t)lane * KC + k] + s;
        out[OFF_EMBSUM + (size_t)lane * KC + k] = ns;
        out[OFF_EMB    + (size_t)lane * KC + k] = ns / fmaxf(cf, 1e-5f);
        if (lane == 0) {
            out[OFF_COUNT + k] = cf;
            float lp = slsum[0] + slsum[1] + slsum[2] + slsum[3];
            atomicAdd(&out[OFF_LOSS], lp * (BETA / ((float)NROWS * (float)DIMS)));
        }
    }
}

extern "C" void kernel_launch(void* const* d_in, const int* in_sizes, int n_in,
                              void* d_out, int out_size, void* d_ws, size_t ws_size,
                              hipStream_t stream) {
    const float* x      = (const float*)d_in[0];
    const float* emb    = (const float*)d_in[1];
    const float* scount = (const float*)d_in[2];
    const float* esum   = (const float*)d_in[3];
    float* out = (float*)d_out;
    float* ws  = (float*)d_ws;

    const bool binned = ws_size >= (size_t)WS_TOTAL_DW * 4;
    if (binned) {
        f16* ehT = (f16*)(ws + WS_EHT);
        f16* elT = (f16*)(ws + WS_ELT);
        int* wsI = (int*)ws;
        vq_prep<<<KC / 64, 256, 0, stream>>>(emb, ws, ehT, elT, wsI + WS_HIST,
                                             ws + WS_SUMACC, out + OFF_LOSS);
        vq_main_t<true><<<NROWS / 128, 256, 0, stream>>>(x, ehT, elT, ws, out,
                                                         wsI + WS_IDX, wsI + WS_HIST);
        vq_scan<<<1, 1024, 0, stream>>>(scount, wsI, out);
        vq_bin<<<NROWS / 256, 256, 0, stream>>>(wsI);
        vq_sumchunk<<<2048, 512, 0, stream>>>(x, ws, esum, out);
    } else {
        f16* ehT = (f16*)(out + OFF_EMBSUM);   // stashed in output, overwritten later
        f16* elT = ehT + KC * DIMS;
        int* idx = (int*)ws + WS_IDX_FB;
        vq_prep<<<KC / 64, 256, 0, stream>>>(emb, ws, ehT, elT, nullptr, nullptr,
                                             out + OFF_LOSS);
        vq_main_t<false><<<NROWS / 128, 256, 0, stream>>>(x, ehT, elT, ws, out,
                                                          idx, nullptr);
        vq_scatter<<<KC, 256, 0, stream>>>(x, ws, idx, scount, esum, out);
    }
}

// Round 15
// 144.075 us; speedup vs baseline: 3.3709x; 1.5274x over previous
//
#include <hip/hip_runtime.h>

typedef _Float16 f16;
typedef _Float16 f16x8 __attribute__((ext_vector_type(8)));
typedef float f32x4 __attribute__((ext_vector_type(4)));

#define NROWS 131072
#define DIMS  64
#define KC    1024
#define BETA  0.25f
#define CHUNK 128          // rows per sum-chunk block

// output offsets (floats)
#define OFF_Q      0
#define OFF_LOSS   8388608
#define OFF_EMB    8388609
#define OFF_COUNT  (8388609 + 65536)
#define OFF_EMBSUM (8388609 + 65536 + 1024)

// ws dword offsets — binned path, 1.856 MB total
#define WS_NORME  0            // float[1024]
#define WS_ET     1024         // float eT[K][64] exact
#define WS_EHT    66560        // f16[65536]
#define WS_ELT    99328        // f16[65536]
#define WS_IDX    132096       // int[131072]
#define WS_HIST   263168       // int[1024]
#define WS_OFF    264192       // int[1025] (pad 1040)
#define WS_CUR    265232       // int[1024]
#define WS_CCH    266256       // int[1025] cumulative chunks (pad 1040)
#define WS_RID    267296       // int[131072]
#define WS_SUMACC 398368       // float[1024][64]
#define WS_TOTAL_DW 463904

// fallback (R4) layout
#define WS_IDX_FB (1024 + 65536)

// 64 blocks x 16 codes (was 16 blocks x 64 codes: 94% of CUs idle,
// latency-bound). Same LDS-transpose pattern, 4 iters instead of 16.
__global__ void vq_prep(const float* __restrict__ emb, float* __restrict__ ws,
                        f16* __restrict__ ehT, f16* __restrict__ elT,
                        int* __restrict__ hist, float* __restrict__ sumacc,
                        float* __restrict__ loss_out) {
    __shared__ float buf[16][65];
    const int t = threadIdx.x;
    const int k0 = blockIdx.x * 16;
    if (hist && blockIdx.x < 4) hist[blockIdx.x * 256 + t] = 0;
    if (sumacc) {
        #pragma unroll
        for (int j = 0; j < 4; ++j) sumacc[blockIdx.x * 1024 + j * 256 + t] = 0.f;
    }
    if (blockIdx.x == 0 && t == 0) *loss_out = 0.f;
    #pragma unroll
    for (int it = 0; it < 4; ++it) {
        int idx = it * 256 + t;
        int kk = idx & 15, d = idx >> 4;
        buf[kk][d] = emb[(size_t)d * KC + k0 + kk];   // 64B runs per d-row
    }
    __syncthreads();
    if (t < 16) {
        float s = 0.f;
        #pragma unroll 8
        for (int d = 0; d < 64; ++d) { float v = buf[t][d]; s += v * v; }
        ws[WS_NORME + k0 + t] = s;
    }
    #pragma unroll
    for (int it = 0; it < 4; ++it) {
        int idx = it * 256 + t;
        int d = idx & 63, kk = idx >> 6;
        float v = buf[kk][d];
        f16 hi = (f16)v;
        f16 lo = (f16)(v - (float)hi);
        ws[WS_ET + (size_t)(k0 + kk) * 64 + d] = v;   // coalesced over d
        ehT[(size_t)(k0 + kk) * 64 + d] = hi;
        elT[(size_t)(k0 + kk) * 64 + d] = lo;
    }
}

// [K5, proven 78us @ VGPR 60] 128 rows/block, 128-code chunks, plain
// 2-barrier loop, single acc chain. FROZEN — do not add epilogue code or acc
// chains: R6/R9/R11 all collapsed to scratch from exactly such additions.
template <bool DMA>
__launch_bounds__(256, 4)
__global__ void vq_main_t(const float* __restrict__ x, const f16* __restrict__ ehT,
                          const f16* __restrict__ elT, const float* __restrict__ ws,
                          float* __restrict__ q_out, int* __restrict__ idxout,
                          int* __restrict__ hist) {
    __shared__ f16 eh[128 * 64];     // XOR-swizzled [code][d]
    __shared__ f16 el[128 * 64];
    __shared__ float nEl[1024];
    __shared__ int best_k[128];

    const int t    = threadIdx.x;
    const int lane = t & 63;
    const int wv   = t >> 6;         // 4 waves, 32 rows each
    const int brow = blockIdx.x * 128;
    const int l15  = lane & 15;
    const int l4   = lane >> 4;

    // preload normE (consumed via MFMA C-operand init)
    #pragma unroll
    for (int j = 0; j < 4; ++j) nEl[t + j * 256] = ws[WS_NORME + t + j * 256];

    // A fragments: rows of x as f16 hi/lo. A layout: row=lane&15, k=(lane>>4)*8+j
    f16x8 ahi[2][2], alo[2][2];
    #pragma unroll
    for (int rt = 0; rt < 2; ++rt) {
        int row = brow + wv * 32 + rt * 16 + l15;
        #pragma unroll
        for (int ks = 0; ks < 2; ++ks) {
            int d0 = ks * 32 + l4 * 8;
            const float* p = x + (size_t)row * 64 + d0;
            float4 v0 = *(const float4*)p;
            float4 v1 = *(const float4*)(p + 4);
            float vv[8] = {v0.x, v0.y, v0.z, v0.w, v1.x, v1.y, v1.z, v1.w};
            f16x8 h, l;
            #pragma unroll
            for (int j = 0; j < 8; ++j) {
                f16 hj = (f16)vv[j];
                h[j] = hj;
                l[j] = (f16)(vv[j] - (float)hj);
            }
            ahi[rt][ks] = h; alo[rt][ks] = l;
        }
    }

    // per-thread pre-swizzled staging source offsets (both-sides rule #21:
    // inverse-swizzled global source + linear LDS dest; read applies same XOR)
    int swz[4];
    #pragma unroll
    for (int it = 0; it < 4; ++it) {
        int n = (it * 256 + t) * 16;
        int code = n >> 7, inner = n & 127;
        swz[it] = (code << 7) | (inner ^ ((code & 7) << 4));
    }

    float bmax[2][4];
    int   bidx[2][4];
    #pragma unroll
    for (int rt = 0; rt < 2; ++rt)
        #pragma unroll
        for (int r = 0; r < 4; ++r) { bmax[rt][r] = -1e30f; bidx[rt][r] = 0; }

    for (int kc0 = 0; kc0 < KC; kc0 += 128) {
        __syncthreads();
        if constexpr (DMA) {
            #pragma unroll
            for (int it = 0; it < 4; ++it) {
                int lo = (it * 256 + wv * 64) * 16;   // wave-uniform base, lane*16 auto
                const char* gh = (const char*)ehT + (size_t)kc0 * 128 + swz[it];
                const char* gl = (const char*)elT + (size_t)kc0 * 128 + swz[it];
                __builtin_amdgcn_global_load_lds(
                    (const __attribute__((address_space(1))) void*)gh,
                    (__attribute__((address_space(3))) void*)((char*)eh + lo), 16, 0, 0);
                __builtin_amdgcn_global_load_lds(
                    (const __attribute__((address_space(1))) void*)gl,
                    (__attribute__((address_space(3))) void*)((char*)el + lo), 16, 0, 0);
            }
        } else {
            #pragma unroll
            for (int it = 0; it < 4; ++it) {
                int n = (it * 256 + t) * 16;
                float4 vh = *(const float4*)((const char*)ehT + (size_t)kc0 * 128 + n);
                float4 vl = *(const float4*)((const char*)elT + (size_t)kc0 * 128 + n);
                *(float4*)((char*)eh + swz[it]) = vh;
                *(float4*)((char*)el + swz[it]) = vl;
            }
        }
        __syncthreads();

        #pragma unroll
        for (int ct = 0; ct < 8; ++ct) {
            int code = ct * 16 + l15;             // B col = lane&15
            f16x8 bh[2], bl[2];
            #pragma unroll
            for (int ks = 0; ks < 2; ++ks) {
                int inner = ks * 64 + l4 * 16;    // k = (lane>>4)*8 + j
                int off = (code << 7) | (inner ^ ((code & 7) << 4));
                bh[ks] = *(const f16x8*)((char*)eh + off);
                bl[ks] = *(const f16x8*)((char*)el + off);
            }
            int gcol = kc0 + code;
            float c0 = -0.5f * nEl[gcol];         // dist = -2*(sim - nE/2): track max
            #pragma unroll
            for (int rt = 0; rt < 2; ++rt) {
                f32x4 acc = {c0, c0, c0, c0};
                acc = __builtin_amdgcn_mfma_f32_16x16x32_f16(ahi[rt][0], bh[0], acc, 0, 0, 0);
                acc = __builtin_amdgcn_mfma_f32_16x16x32_f16(ahi[rt][1], bh[1], acc, 0, 0, 0);
                acc = __builtin_amdgcn_mfma_f32_16x16x32_f16(alo[rt][0], bh[0], acc, 0, 0, 0);
                acc = __builtin_amdgcn_mfma_f32_16x16x32_f16(alo[rt][1], bh[1], acc, 0, 0, 0);
                acc = __builtin_amdgcn_mfma_f32_16x16x32_f16(ahi[rt][0], bl[0], acc, 0, 0, 0);
                acc = __builtin_amdgcn_mfma_f32_16x16x32_f16(ahi[rt][1], bl[1], acc, 0, 0, 0);
                // C/D layout: col = lane&15, row = (lane>>4)*4 + reg
                #pragma unroll
                for (int r = 0; r < 4; ++r) {
                    if (acc[r] > bmax[rt][r]) { bmax[rt][r] = acc[r]; bidx[rt][r] = gcol; }
                }
            }
        }
    }

    // argmax reduce across the 16 lanes holding the same row (tie -> lower k)
    #pragma unroll
    for (int rt = 0; rt < 2; ++rt) {
        #pragma unroll
        for (int r = 0; r < 4; ++r) {
            float a = bmax[rt][r]; int k = bidx[rt][r];
            #pragma unroll
            for (int m = 1; m <= 8; m <<= 1) {
                float a2 = __shfl_xor(a, m, 64);
                int   k2 = __shfl_xor(k, m, 64);
                if (a2 > a || (a2 == a && k2 < k)) { a = a2; k = k2; }
            }
            if (l15 == 0) {
                int rloc = wv * 32 + rt * 16 + l4 * 4 + r;
                best_k[rloc] = k;
                if (hist) atomicAdd(&hist[k], 1);
            }
        }
    }
    __syncthreads();

    // epilogue: idx write + coalesced q gather from exact fp32 eT.
    if (t < 128) idxout[brow + t] = best_k[t];
    const float* eT = ws + WS_ET;
    #pragma unroll 4
    for (int it = 0; it < 32; ++it) {
        int r = it * 4 + wv;
        int k = best_k[r];                        // wave-uniform broadcast
        q_out[(size_t)(brow + r) * 64 + lane] = eT[(size_t)k * 64 + lane];
    }
}

// 1 block, 1024 threads: shfl prefix scans of hist (-> offsets/cursors) and
// ceil(hist/CHUNK) (-> cumulative chunk table); writes count output.
__global__ void vq_scan(const float* __restrict__ scount, int* __restrict__ wsI,
                        float* __restrict__ out) {
    __shared__ int wincl[16];
    __shared__ int wincl2[16];
    const int t = threadIdx.x;
    const int lane = t & 63, wv = t >> 6;
    int h = wsI[WS_HIST + t];
    int m = (h + CHUNK - 1) >> 7;    // chunks for this code
    int v = h, u = m;
    #pragma unroll
    for (int o = 1; o < 64; o <<= 1) {
        int a = __shfl_up(v, o, 64);
        int b = __shfl_up(u, o, 64);
        if (lane >= o) { v += a; u += b; }
    }
    if (lane == 63) { wincl[wv] = v; wincl2[wv] = u; }
    __syncthreads();
    if (t < 16) {
        int s = wincl[t], s2 = wincl2[t];
        #pragma unroll
        for (int o = 1; o < 16; o <<= 1) {
            int a = __shfl_up(s, o, 64);
            int b = __shfl_up(s2, o, 64);
            if (t >= o) { s += a; s2 += b; }
        }
        wincl[t] = s; wincl2[t] = s2;
    }
    __syncthreads();
    int incl  = v + (wv ? wincl[wv - 1] : 0);
    int incl2 = u + (wv ? wincl2[wv - 1] : 0);
    wsI[WS_OFF + t] = incl - h;
    wsI[WS_CUR + t] = incl - h;
    wsI[WS_CCH + t] = incl2 - m;
    if (t == 1023) { wsI[WS_OFF + 1024] = incl; wsI[WS_CCH + 1024] = incl2; }
    out[OFF_COUNT + t] = scount[t] + (float)h;
}

// bin rows by code: 131072 same-line cursor atomics + rowid writes.
__global__ void vq_bin(int* __restrict__ wsI) {
    const int i = blockIdx.x * blockDim.x + threadIdx.x;
    int k = wsI[WS_IDX + i];
    int pos = atomicAdd(&wsI[WS_CUR + k], 1);
    wsI[WS_RID + pos] = i;
}

// one block per CHUNK of a bin (skew-proof): partial sums -> SUMACC atomics.
__launch_bounds__(512)
__global__ void vq_sumchunk(const float* __restrict__ x, float* __restrict__ ws,
                            float* __restrict__ out) {
    __shared__ float ssum[8][64];
    __shared__ float sl[8];
    const int t    = threadIdx.x;
    const int lane = t & 63;
    const int wv   = t >> 6;
    int* wsI = (int*)ws;
    const int c = blockIdx.x;
    if (c >= wsI[WS_CCH + 1024]) return;
    // binary search: largest k with cch[k] <= c
    int lo = 0, hi = 1024;
    while (hi - lo > 1) {
        int mid = (lo + hi) >> 1;
        if (wsI[WS_CCH + mid] <= c) lo = mid; else hi = mid;
    }
    const int k    = lo;
    const int base = wsI[WS_OFF + k] + (c - wsI[WS_CCH + k]) * CHUNK;
    const int endr = min(base + CHUNK, wsI[WS_OFF + k + 1]);
    const int* rid = wsI + WS_RID;
    const float ek = ws[WS_ET + (size_t)k * 64 + lane];

    float sA = 0.f, sB = 0.f, lA = 0.f, lB = 0.f;
    int i = base + wv;
    for (; i + 8 < endr; i += 16) {
        int rA = rid[i], rB = rid[i + 8];
        float xA = x[(size_t)rA * 64 + lane];
        float xB = x[(size_t)rB * 64 + lane];
        sA += xA; float dA = xA - ek; lA += dA * dA;
        sB += xB; float dB = xB - ek; lB += dB * dB;
    }
    if (i < endr) {
        int rA = rid[i];
        float xA = x[(size_t)rA * 64 + lane];
        sA += xA; float dA = xA - ek; lA += dA * dA;
    }
    float sum = sA + sB, ls = lA + lB;
    #pragma unroll
    for (int o = 32; o > 0; o >>= 1) ls += __shfl_down(ls, o);
    ssum[wv][lane] = sum;
    if (lane == 0) sl[wv] = ls;
    __syncthreads();
    if (wv == 0) {
        float s = 0.f;
        #pragma unroll
        for (int w = 0; w < 8; ++w) s += ssum[w][lane];
        atomicAdd(&ws[WS_SUMACC + (size_t)k * 64 + lane], s);   // coalesced line
        if (lane == 0) {
            float lp = 0.f;
            #pragma unroll
            for (int w = 0; w < 8; ++w) lp += sl[w];
            atomicAdd(&out[OFF_LOSS], lp * (BETA / ((float)NROWS * (float)DIMS)));
        }
    }
}

// finalize: transpose SUMACC[k][d] -> out[D][K] embsum/emb.
// 64 blocks x 16 codes (was 16 blocks: latency-bound on 256 CUs).
__global__ void vq_fin(const float* __restrict__ ws, const float* __restrict__ esum,
                       float* __restrict__ out) {
    __shared__ float tile[16][65];
    const int t = threadIdx.x;
    const int k0 = blockIdx.x * 16;
    #pragma unroll
    for (int it = 0; it < 4; ++it) {
        int idx = it * 256 + t;
        int kk = idx >> 6, d = idx & 63;
        tile[kk][d] = ws[WS_SUMACC + (size_t)(k0 + kk) * 64 + d];   // coalesced
    }
    __syncthreads();
    #pragma unroll
    for (int it = 0; it < 4; ++it) {
        int idx = it * 256 + t;
        int d = idx >> 4, kk = idx & 15;
        int k = k0 + kk;
        float ns = esum[(size_t)d * KC + k] + tile[kk][d];
        float cf = out[OFF_COUNT + k];
        out[OFF_EMBSUM + (size_t)d * KC + k] = ns;
        out[OFF_EMB    + (size_t)d * KC + k] = ns / fmaxf(cf, 1e-5f);
    }
}

// fallback: scan-based cluster update, one block per code (proven R4 path).
__launch_bounds__(256)
__global__ void vq_scatter(const float* __restrict__ x, const float* __restrict__ ws,
                           const int* __restrict__ idx, const float* __restrict__ scount,
                           const float* __restrict__ esum, float* __restrict__ out) {
    __shared__ float ssum[4][64];
    __shared__ float slsum[4];
    __shared__ int   scnt[4];
    const int k    = blockIdx.x;
    const int t    = threadIdx.x;
    const int lane = t & 63;
    const int wv   = t >> 6;
    const float ek = ws[WS_ET + (size_t)k * 64 + lane];
    const int4* idx4 = (const int4*)idx;
    float sum = 0.f, lsum = 0.f;
    int cnt = 0;
    const int base = wv * (NROWS / 16);
    for (int i0 = 0; i0 < NROWS / 16; i0 += 64) {
        int4 v = idx4[base + i0 + lane];
        #pragma unroll
        for (int j = 0; j < 4; ++j) {
            int vj = (j == 0) ? v.x : (j == 1) ? v.y : (j == 2) ? v.z : v.w;
            unsigned long long m = __ballot(vj == k);
            cnt += (int)__popcll(m);
            while (m) {
                int b = __builtin_ctzll(m);
                m &= m - 1;
                int row = (base + i0 + b) * 4 + j;
                float xv = x[(size_t)row * 64 + lane];
                sum += xv;
                float diff = xv - ek;
                lsum += diff * diff;
            }
        }
    }
    #pragma unroll
    for (int o = 32; o > 0; o >>= 1) lsum += __shfl_down(lsum, o);
    ssum[wv][lane] = sum;
    if (lane == 0) { scnt[wv] = cnt; slsum[wv] = lsum; }
    __syncthreads();
    if (wv == 0) {
        float s = ssum[0][lane] + ssum[1][lane] + ssum[2][lane] + ssum[3][lane];
        int   c = scnt[0] + scnt[1] + scnt[2] + scnt[3];
        float cf = scount[k] + (float)c;
        float ns = esum[(size_t)lane * KC + k] + s;
        out[OFF_EMBSUM + (size_t)lane * KC + k] = ns;
        out[OFF_EMB    + (size_t)lane * KC + k] = ns / fmaxf(cf, 1e-5f);
        if (lane == 0) {
            out[OFF_COUNT + k] = cf;
            float lp = slsum[0] + slsum[1] + slsum[2] + slsum[3];
            atomicAdd(&out[OFF_LOSS], lp * (BETA / ((float)NROWS * (float)DIMS)));
        }
    }
}

extern "C" void kernel_launch(void* const* d_in, const int* in_sizes, int n_in,
                              void* d_out, int out_size, void* d_ws, size_t ws_size,
                              hipStream_t stream) {
    const float* x      = (const float*)d_in[0];
    const float* emb    = (const float*)d_in[1];
    const float* scount = (const float*)d_in[2];
    const float* esum   = (const float*)d_in[3];
    float* out = (float*)d_out;
    float* ws  = (float*)d_ws;

    const bool binned = ws_size >= (size_t)WS_TOTAL_DW * 4;
    if (binned) {
        f16* ehT = (f16*)(ws + WS_EHT);
        f16* elT = (f16*)(ws + WS_ELT);
        int* wsI = (int*)ws;
        vq_prep<<<KC / 16, 256, 0, stream>>>(emb, ws, ehT, elT, wsI + WS_HIST,
                                             ws + WS_SUMACC, out + OFF_LOSS);
        vq_main_t<true><<<NROWS / 128, 256, 0, stream>>>(x, ehT, elT, ws, out,
                                                         wsI + WS_IDX, wsI + WS_HIST);
        vq_scan<<<1, 1024, 0, stream>>>(scount, wsI, out);
        vq_bin<<<NROWS / 256, 256, 0, stream>>>(wsI);
        vq_sumchunk<<<2048, 512, 0, stream>>>(x, ws, out);
        vq_fin<<<KC / 16, 256, 0, stream>>>(ws, esum, out);
    } else {
        f16* ehT = (f16*)(out + OFF_EMBSUM);   // stashed in output, overwritten later
        f16* elT = ehT + KC * DIMS;
        int* idx = (int*)ws + WS_IDX_FB;
        vq_prep<<<KC / 16, 256, 0, stream>>>(emb, ws, ehT, elT, nullptr, nullptr,
                                             out + OFF_LOSS);
        vq_main_t<false><<<NROWS / 128, 256, 0, stream>>>(x, ehT, elT, ws, out,
                                                          idx, nullptr);
        vq_scatter<<<KC, 256, 0, stream>>>(x, ws, idx, scount, esum, out);
    }
}